// Round 1
// baseline (1195.296 us; speedup 1.0000x reference)
//
#include <hip/hip_runtime.h>
#include <math.h>

#define NN 8000   // nodes
#define CD 64     // node feature dim / C_OUT
#define DG 16     // neighbors per node
#define HD 128    // GRU hidden
#define G3 384    // 3*HD
#define TT 4      // walk steps

__device__ __forceinline__ double sig64(double x){ return 1.0/(1.0+exp(-x)); }

// XG precompute: out[n][g] = b[g] + sum_c A[n][c]*W[c][g], accumulated in f64.
template<bool F64OUT>
__global__ __launch_bounds__(384) void xg_kernel(const float* __restrict__ A,
    const float* __restrict__ W, const float* __restrict__ b,
    double* __restrict__ outd, float* __restrict__ outf)
{
    __shared__ float a_s[8][64];
    const int g  = threadIdx.x;        // 0..383
    const int n0 = blockIdx.x * 8;
    for (int idx = threadIdx.x; idx < 8*64; idx += 384)
        a_s[idx>>6][idx&63] = A[(size_t)n0*64 + idx];
    __syncthreads();
    double acc[8];
    const double bg = (double)b[g];
#pragma unroll
    for (int j=0;j<8;j++) acc[j] = bg;
    for (int c=0;c<64;c++){
        const double w = (double)W[c*G3 + g];
#pragma unroll
        for (int j=0;j<8;j++) acc[j] += (double)a_s[j][c]*w;
    }
#pragma unroll
    for (int j=0;j<8;j++){
        if (F64OUT) outd[(size_t)(n0+j)*G3 + g] = acc[j];
        else        outf[(size_t)(n0+j)*G3 + g] = (float)acc[j];
    }
}

__global__ void cvt_kernel(const float* __restrict__ s, double* __restrict__ d, int n){
    int i = blockIdx.x*blockDim.x + threadIdx.x;
    if (i < n) d[i] = (double)s[i];
}

// One wave (64 lanes) per node; 4 waves per block. Whole T-loop in one kernel.
__global__ __launch_bounds__(256) void walk_kernel(
    const int*   __restrict__ nbrs,  const float* __restrict__ noise,
    const double* __restrict__ XGd,  const float* __restrict__ XGw,
    const double* __restrict__ Wh64,
    const float* __restrict__ dbh,   const float* __restrict__ dWo, const float* __restrict__ dbo,
    const float* __restrict__ wWh,   const float* __restrict__ wbh,
    const float* __restrict__ wWo,   const float* __restrict__ wbo,
    float* __restrict__ out)
{
    __shared__ double h_s [4][HD];   // d-GRU hidden (f64), per wave
    __shared__ float  hw_s[4][HD];   // w-GRU hidden (f32), per wave
    __shared__ double sc_s[4][DG];   // candidate logits
    __shared__ double wo0_s[HD];     // dWo[:,0] in f64 (shared by all 4 waves)

    const int wid  = threadIdx.x >> 6;
    const int lane = threadIdx.x & 63;
    const int node = blockIdx.x*4 + wid;
    const int i0 = lane, i1 = lane + 64;

    if (threadIdx.x < HD) wo0_s[threadIdx.x] = (double)dWo[threadIdx.x*CD];

    h_s [wid][i0] = 0.0;  h_s [wid][i1] = 0.0;
    hw_s[wid][i0] = 0.f;  hw_s[wid][i1] = 0.f;

    // hg[m] holds gate pre-act g = lane + 64*m ; note for dim i the (r,z,n) offsets
    // i, i+128, i+256 are all congruent to lane mod 64 -> lane-local, registers only.
    double hg[6];  float hgw[6];
    double dbh_r[6]; float wbh_r[6];
#pragma unroll
    for (int m=0;m<6;m++){
        dbh_r[m] = (double)dbh[lane+64*m];
        wbh_r[m] = wbh[lane+64*m];
        hg[m]  = dbh_r[m];     // hg of h=0
        hgw[m] = wbh_r[m];
    }
    const double dbo0 = (double)dbo[0];
    int cur = node;
    __syncthreads();

    for (int t=0;t<TT;t++){
        // ---- extend d-prefix and w-walk with attr[cur] (uses PREVIOUS hg) ----
        const double* xg = XGd + (size_t)cur*G3;
        const float*  xw = XGw + (size_t)cur*G3;
        double hn0, hn1; float hwn0, hwn1;
        {
            double r = sig64(xg[i0]     + hg[0]);
            double z = sig64(xg[i0+128] + hg[2]);
            double n = tanh (xg[i0+256] + r*hg[4]);
            hn0 = (1.0-z)*n + z*h_s[wid][i0];
            r = sig64(xg[i1]     + hg[1]);
            z = sig64(xg[i1+128] + hg[3]);
            n = tanh (xg[i1+256] + r*hg[5]);
            hn1 = (1.0-z)*n + z*h_s[wid][i1];
        }
        {
            float r = 1.f/(1.f+expf(-(xw[i0]     + hgw[0])));
            float z = 1.f/(1.f+expf(-(xw[i0+128] + hgw[2])));
            float n = tanhf(xw[i0+256] + r*hgw[4]);
            hwn0 = (1.f-z)*n + z*hw_s[wid][i0];
            r = 1.f/(1.f+expf(-(xw[i1]     + hgw[1])));
            z = 1.f/(1.f+expf(-(xw[i1+128] + hgw[3])));
            n = tanhf(xw[i1+256] + r*hgw[5]);
            hwn1 = (1.f-z)*n + z*hw_s[wid][i1];
        }
        h_s [wid][i0]=hn0;  h_s [wid][i1]=hn1;
        hw_s[wid][i0]=hwn0; hw_s[wid][i1]=hwn1;
        __syncthreads();   // cross-lane h reads in the matvec below

        // ---- matvecs: hg = dbh + h@dWh (f64) ; hgw = wbh + hw@wWh (f32) ----
        double acc[6]; float accw[6];
#pragma unroll
        for (int m=0;m<6;m++){ acc[m]=dbh_r[m]; accw[m]=wbh_r[m]; }
        {
            const double* wp  = Wh64 + lane;
            const float*  wwp = wWh  + lane;
            for (int k=0;k<HD;k++){
                const double hk  = h_s [wid][k];
                const float  hwk = hw_s[wid][k];
#pragma unroll
                for (int m=0;m<6;m++){
                    acc[m]  += hk  * wp [(size_t)k*G3 + 64*m];
                    accw[m] += hwk * wwp[(size_t)k*G3 + 64*m];
                }
            }
        }
#pragma unroll
        for (int m=0;m<6;m++){ hg[m]=acc[m]; hgw[m]=accw[m]; }

        // ---- 16 candidates share hg; each = gating + dot with dWo[:,0] ----
        int nbrv = (lane < DG) ? nbrs[(size_t)cur*DG + lane] : 0;
        for (int d=0; d<DG; d++){
            const int nd = __shfl(nbrv, d);
            const double* xc = XGd + (size_t)nd*G3;
            double r = sig64(xc[i0]     + hg[0]);
            double z = sig64(xc[i0+128] + hg[2]);
            double n = tanh (xc[i0+256] + r*hg[4]);
            double part = ((1.0-z)*n + z*h_s[wid][i0]) * wo0_s[i0];
            r = sig64(xc[i1]     + hg[1]);
            z = sig64(xc[i1+128] + hg[3]);
            n = tanh (xc[i1+256] + r*hg[5]);
            part += ((1.0-z)*n + z*h_s[wid][i1]) * wo0_s[i1];
#pragma unroll
            for (int off=32; off>0; off>>=1) part += __shfl_xor(part, off);
            if (lane == 0) sc_s[wid][d] = part + dbo0;
        }
        __syncthreads();

        // ---- logsumexp-normalize, add noise, argmax (first-max tiebreak) ----
        double v = (lane < DG) ? sc_s[wid][lane] : -1e300;
        double mx = v;
#pragma unroll
        for (int off=32; off>0; off>>=1) mx = fmax(mx, __shfl_xor(mx, off));
        double e = (lane < DG) ? exp(v - mx) : 0.0;
        double ssum = e;
#pragma unroll
        for (int off=32; off>0; off>>=1) ssum += __shfl_xor(ssum, off);
        const double norm = mx + log(ssum);

        double noisy = -1e300;
        if (lane < DG)
            noisy = exp(v - norm) + 0.01 * (double)noise[((size_t)t*NN + node)*DG + lane];
        int idx = lane;
#pragma unroll
        for (int off=32; off>0; off>>=1){
            double ov = __shfl_xor(noisy, off);
            int    oi = __shfl_xor(idx,   off);
            if (ov > noisy || (ov == noisy && oi < idx)){ noisy = ov; idx = oi; }
        }
        if (lane == 0) out[NN*CD + node*TT + t] = (float)(sc_s[wid][idx] - norm);
        cur = __shfl(nbrv, idx);
    }

    // ---- final w-extend with cur_T, then v_out = h_w @ wWo + wbo ----
    {
        const float* xw = XGw + (size_t)cur*G3;
        float r = 1.f/(1.f+expf(-(xw[i0]     + hgw[0])));
        float z = 1.f/(1.f+expf(-(xw[i0+128] + hgw[2])));
        float n = tanhf(xw[i0+256] + r*hgw[4]);
        float hwn0 = (1.f-z)*n + z*hw_s[wid][i0];
        r = 1.f/(1.f+expf(-(xw[i1]     + hgw[1])));
        z = 1.f/(1.f+expf(-(xw[i1+128] + hgw[3])));
        n = tanhf(xw[i1+256] + r*hgw[5]);
        float hwn1 = (1.f-z)*n + z*hw_s[wid][i1];
        hw_s[wid][i0]=hwn0; hw_s[wid][i1]=hwn1;
    }
    __syncthreads();
    {
        float acc = wbo[lane];                 // CD == 64 == wave width
        const float* wcol = wWo + lane;
        for (int i=0;i<HD;i++) acc += hw_s[wid][i] * wcol[(size_t)i*CD];
        out[(size_t)node*CD + lane] = acc;
    }
}

extern "C" void kernel_launch(void* const* d_in, const int* in_sizes, int n_in,
                              void* d_out, int out_size, void* d_ws, size_t ws_size,
                              hipStream_t stream)
{
    const float* attr  = (const float*)d_in[0];
    const int*   nbrs  = (const int*)  d_in[1];
    const float* noise = (const float*)d_in[2];
    const float* dWx = (const float*)d_in[3];
    const float* dWh = (const float*)d_in[4];
    const float* dbx = (const float*)d_in[5];
    const float* dbh = (const float*)d_in[6];
    const float* dWo = (const float*)d_in[7];
    const float* dbo = (const float*)d_in[8];
    const float* wWx = (const float*)d_in[9];
    const float* wWh = (const float*)d_in[10];
    const float* wbx = (const float*)d_in[11];
    const float* wbh = (const float*)d_in[12];
    const float* wWo = (const float*)d_in[13];
    const float* wbo = (const float*)d_in[14];
    float* out = (float*)d_out;

    char* ws = (char*)d_ws;
    double* XGd  = (double*)(ws);                         // 8000*384*8  = 24.576 MB
    float*  XGw  = (float*) (ws + (size_t)NN*G3*8);       // 8000*384*4  = 12.288 MB
    double* Wh64 = (double*)(ws + (size_t)NN*G3*12);      // 128*384*8   =  0.393 MB

    xg_kernel<true ><<<NN/8, G3, 0, stream>>>(attr, dWx, dbx, XGd, nullptr);
    xg_kernel<false><<<NN/8, G3, 0, stream>>>(attr, wWx, wbx, nullptr, XGw);
    cvt_kernel<<<(HD*G3+255)/256, 256, 0, stream>>>(dWh, Wh64, HD*G3);
    walk_kernel<<<NN/4, 256, 0, stream>>>(nbrs, noise, XGd, XGw, Wh64,
                                          dbh, dWo, dbo, wWh, wbh, wWo, wbo, out);
}